// Round 1
// baseline (1518.866 us; speedup 1.0000x reference)
//
#include <hip/hip_runtime.h>

// Problem constants (from reference): N=100000 nodes, E=1600000 edges, D=64.
#define D_FEAT 64

// One edge handled by 16 threads; each thread loads float4 of feat[col[e]]
// and atomically accumulates into out[row[e]]. Lane part==0 bumps deg.
__global__ void gnn_scatter_kernel(const float* __restrict__ feat,
                                   const int* __restrict__ row,
                                   const int* __restrict__ col,
                                   float* __restrict__ accum,   // = d_out, pre-zeroed
                                   float* __restrict__ deg,     // pre-zeroed
                                   int n_edges) {
    int gid = blockIdx.x * blockDim.x + threadIdx.x;
    int e = gid >> 4;          // edge index
    int part = gid & 15;       // which float4 of the 64-dim feature
    if (e >= n_edges) return;
    int r = row[e];
    int c = col[e];
    const float4 v = *reinterpret_cast<const float4*>(feat + (size_t)c * D_FEAT + part * 4);
    float* dst = accum + (size_t)r * D_FEAT + part * 4;
    unsafeAtomicAdd(dst + 0, v.x);
    unsafeAtomicAdd(dst + 1, v.y);
    unsafeAtomicAdd(dst + 2, v.z);
    unsafeAtomicAdd(dst + 3, v.w);
    if (part == 0) {
        unsafeAtomicAdd(deg + r, 1.0f);
    }
}

// out = feat + accum * (1 / max(deg, 1)), in place on d_out.
__global__ void gnn_finalize_kernel(const float* __restrict__ feat,
                                    const float* __restrict__ deg,
                                    float* __restrict__ out,    // holds accum on entry
                                    int n_nodes) {
    int gid = blockIdx.x * blockDim.x + threadIdx.x;
    int n = gid >> 4;
    int part = gid & 15;
    if (n >= n_nodes) return;
    float inv = 1.0f / fmaxf(deg[n], 1.0f);
    size_t off = (size_t)n * D_FEAT + part * 4;
    float4 a = *reinterpret_cast<const float4*>(out + off);
    float4 f = *reinterpret_cast<const float4*>(feat + off);
    float4 o;
    o.x = f.x + a.x * inv;
    o.y = f.y + a.y * inv;
    o.z = f.z + a.z * inv;
    o.w = f.w + a.w * inv;
    *reinterpret_cast<float4*>(out + off) = o;
}

extern "C" void kernel_launch(void* const* d_in, const int* in_sizes, int n_in,
                              void* d_out, int out_size, void* d_ws, size_t ws_size,
                              hipStream_t stream) {
    const float* feat = (const float*)d_in[0];
    const int* row = (const int*)d_in[1];
    const int* col = (const int*)d_in[2];
    float* out = (float*)d_out;
    float* deg = (float*)d_ws;

    const int n_nodes = in_sizes[0] / D_FEAT;
    const int n_edges = in_sizes[1];

    // Zero the accumulator (d_out) and deg (workspace). Async memsets are
    // graph-capture safe.
    hipMemsetAsync(d_out, 0, (size_t)out_size * sizeof(float), stream);
    hipMemsetAsync(d_ws, 0, (size_t)n_nodes * sizeof(float), stream);

    // Scatter: 16 threads per edge.
    {
        long long total = (long long)n_edges * 16;
        int block = 256;
        int grid = (int)((total + block - 1) / block);
        gnn_scatter_kernel<<<grid, block, 0, stream>>>(feat, row, col, out, deg, n_edges);
    }

    // Finalize: 16 threads per node.
    {
        long long total = (long long)n_nodes * 16;
        int block = 256;
        int grid = (int)((total + block - 1) / block);
        gnn_finalize_kernel<<<grid, block, 0, stream>>>(feat, deg, out, n_nodes);
    }
}

// Round 2
// 336.850 us; speedup vs baseline: 4.5090x; 4.5090x over previous
//
#include <hip/hip_runtime.h>

// N=100000 nodes, E=1600000 edges, D=64.
#define D_FEAT 64
#define SCAN_BLOCK 256

// ---------------- Phase A: per-row edge counts (int atomics) ----------------
__global__ void count_kernel(const int* __restrict__ row, int* __restrict__ counts,
                             int n_edges) {
    int e = blockIdx.x * blockDim.x + threadIdx.x;
    if (e < n_edges) atomicAdd(counts + row[e], 1);
}

// ---------------- Phase B: hierarchical exclusive scan ----------------
// B1: per-block sums of counts
__global__ void scan_blocksum_kernel(const int* __restrict__ counts, int* __restrict__ blocksums,
                                     int n) {
    __shared__ int s[SCAN_BLOCK];
    int t = threadIdx.x;
    int i = blockIdx.x * SCAN_BLOCK + t;
    s[t] = (i < n) ? counts[i] : 0;
    __syncthreads();
    for (int o = SCAN_BLOCK / 2; o > 0; o >>= 1) {
        if (t < o) s[t] += s[t + o];
        __syncthreads();
    }
    if (t == 0) blocksums[blockIdx.x] = s[0];
}

// B2: single-block exclusive scan of block sums (nb <= 512)
__global__ void scan_top_kernel(int* __restrict__ blocksums, int* __restrict__ offsets,
                                int nb, int n_nodes) {
    __shared__ int s[512];
    int t = threadIdx.x;
    int v = (t < nb) ? blocksums[t] : 0;
    s[t] = v;
    __syncthreads();
    for (int o = 1; o < 512; o <<= 1) {
        int x = (t >= o) ? s[t - o] : 0;
        __syncthreads();
        s[t] += x;
        __syncthreads();
    }
    if (t < nb) blocksums[t] = s[t] - v;  // exclusive block offset
    if (t == 0) offsets[n_nodes] = s[511];  // total == n_edges
}

// B3: per-block exclusive scan + block offset -> offsets & cursor
__global__ void scan_final_kernel(const int* __restrict__ counts, const int* __restrict__ blocksums,
                                  int* __restrict__ offsets, int* __restrict__ cursor, int n) {
    __shared__ int s[SCAN_BLOCK];
    int t = threadIdx.x;
    int i = blockIdx.x * SCAN_BLOCK + t;
    int v = (i < n) ? counts[i] : 0;
    s[t] = v;
    __syncthreads();
    for (int o = 1; o < SCAN_BLOCK; o <<= 1) {
        int x = (t >= o) ? s[t - o] : 0;
        __syncthreads();
        s[t] += x;
        __syncthreads();
    }
    if (i < n) {
        int excl = s[t] - v + blocksums[blockIdx.x];
        offsets[i] = excl;
        cursor[i] = excl;
    }
}

// ---------------- Phase C: scatter col indices into CSR order ----------------
__global__ void fill_kernel(const int* __restrict__ row, const int* __restrict__ col,
                            int* __restrict__ cursor, int* __restrict__ sorted_col,
                            int n_edges) {
    int e = blockIdx.x * blockDim.x + threadIdx.x;
    if (e < n_edges) {
        int pos = atomicAdd(cursor + row[e], 1);
        sorted_col[pos] = col[e];
    }
}

// ---------------- Phase D: one wave per row, gather + reduce ----------------
__global__ void aggregate_kernel(const float* __restrict__ feat,
                                 const int* __restrict__ offsets,
                                 const int* __restrict__ sorted_col,
                                 float* __restrict__ out, int n_nodes) {
    int wave = (blockIdx.x * blockDim.x + threadIdx.x) >> 6;
    int lane = threadIdx.x & 63;
    if (wave >= n_nodes) return;
    int start = offsets[wave];
    int end = offsets[wave + 1];
    float acc = 0.0f;
    int i = start;
    // 4-deep unroll to keep multiple gathers in flight
    for (; i + 4 <= end; i += 4) {
        int c0 = sorted_col[i + 0];
        int c1 = sorted_col[i + 1];
        int c2 = sorted_col[i + 2];
        int c3 = sorted_col[i + 3];
        float v0 = feat[(size_t)c0 * D_FEAT + lane];
        float v1 = feat[(size_t)c1 * D_FEAT + lane];
        float v2 = feat[(size_t)c2 * D_FEAT + lane];
        float v3 = feat[(size_t)c3 * D_FEAT + lane];
        acc += v0 + v1 + v2 + v3;
    }
    for (; i < end; ++i) {
        acc += feat[(size_t)sorted_col[i] * D_FEAT + lane];
    }
    float inv = 1.0f / fmaxf((float)(end - start), 1.0f);
    size_t off = (size_t)wave * D_FEAT + lane;
    out[off] = feat[off] + acc * inv;
}

extern "C" void kernel_launch(void* const* d_in, const int* in_sizes, int n_in,
                              void* d_out, int out_size, void* d_ws, size_t ws_size,
                              hipStream_t stream) {
    const float* feat = (const float*)d_in[0];
    const int* row = (const int*)d_in[1];
    const int* col = (const int*)d_in[2];
    float* out = (float*)d_out;

    const int n_nodes = in_sizes[0] / D_FEAT;
    const int n_edges = in_sizes[1];
    const int nb = (n_nodes + SCAN_BLOCK - 1) / SCAN_BLOCK;  // 391 for N=100000

    // Workspace layout (all int32):
    char* ws = (char*)d_ws;
    int* counts     = (int*)(ws);                                   // [n_nodes]
    int* offsets    = (int*)(ws + (size_t)n_nodes * 4);             // [n_nodes+1]
    int* cursor     = (int*)(ws + (size_t)(2 * n_nodes + 1) * 4);   // [n_nodes]
    int* sorted_col = (int*)(ws + (size_t)(3 * n_nodes + 1) * 4);   // [n_edges]
    int* blocksums  = (int*)(ws + (size_t)(3 * n_nodes + 1 + n_edges) * 4);  // [<=512]

    hipMemsetAsync(counts, 0, (size_t)n_nodes * 4, stream);

    {
        int block = 256, grid = (n_edges + block - 1) / block;
        count_kernel<<<grid, block, 0, stream>>>(row, counts, n_edges);
    }
    scan_blocksum_kernel<<<nb, SCAN_BLOCK, 0, stream>>>(counts, blocksums, n_nodes);
    scan_top_kernel<<<1, 512, 0, stream>>>(blocksums, offsets, nb, n_nodes);
    scan_final_kernel<<<nb, SCAN_BLOCK, 0, stream>>>(counts, blocksums, offsets, cursor, n_nodes);
    {
        int block = 256, grid = (n_edges + block - 1) / block;
        fill_kernel<<<grid, block, 0, stream>>>(row, col, cursor, sorted_col, n_edges);
    }
    {
        long long total = (long long)n_nodes * 64;  // one wave per node
        int block = 256;
        int grid = (int)((total + block - 1) / block);
        aggregate_kernel<<<grid, block, 0, stream>>>(feat, offsets, sorted_col, out, n_nodes);
    }
}